// Round 6
// baseline (441.637 us; speedup 1.0000x reference)
//
#include <hip/hip_runtime.h>
#include <hip/hip_bf16.h>

#define DIN   256
#define HID   512
#define NBAT  32
#define NSEQ  1024
#define SCALEF (1.0f / 2304.0f)

typedef __attribute__((ext_vector_type(4))) float f32x4;
typedef __attribute__((ext_vector_type(8))) short bf16x8;
typedef unsigned short u16;

__device__ __forceinline__ u16 f2bf(float f) {
    union { float f; unsigned u; } v; v.f = f;
    unsigned r = v.u + 0x7fffu + ((v.u >> 16) & 1u);   // RTNE
    return (u16)(r >> 16);
}

__device__ __forceinline__ float bf2f(u16 b) {
    union { unsigned u; float f; } v; v.u = ((unsigned)b) << 16;
    return v.f;
}

__device__ __forceinline__ void g2lds16(const void* g, void* l) {
    __builtin_amdgcn_global_load_lds(
        (const __attribute__((address_space(1))) void*)g,
        (__attribute__((address_space(3))) void*)l,
        16, 0, 0);
}

// ---------------------------------------------------------------------------
__global__ __launch_bounds__(256) void prep_x(const float* __restrict__ x,
                                              u16* __restrict__ xb) {
    long i = (long)blockIdx.x * 256 + threadIdx.x;
    const long n4 = (long)NBAT * NSEQ * DIN / 4;
    if (i < n4) {
        float4 v = ((const float4*)x)[i];
        ushort4 o;
        o.x = f2bf(v.x); o.y = f2bf(v.y); o.z = f2bf(v.z); o.w = f2bf(v.w);
        ((ushort4*)xb)[i] = o;
    }
}

__global__ __launch_bounds__(256) void prep_w(
    const float* __restrict__ Wv, const float* __restrict__ bv,
    const float* __restrict__ Wk, const float* __restrict__ bk,
    const float* __restrict__ Wq, const float* __restrict__ bq,
    u16* __restrict__ Wtb, float* __restrict__ biascat) {
    int i = blockIdx.x * 256 + threadIdx.x;
    if (i < 1536 * 256) {
        int n = i >> 8, k = i & 255;
        const float* W = (n < 512) ? Wv : ((n < 1024) ? Wk : Wq);
        Wtb[i] = f2bf(W[k * 512 + (n & 511)]);
    }
    if (i < 1536) {
        biascat[i] = (i < 512) ? bv[i] : ((i < 1024) ? bk[i - 512] : bq[i - 1024]);
    }
}

// ---------------------------------------------------------------------------
// qkv projection GEMM (round-5 verified): 128x128 tile, BK=64, T2 swizzle.
__global__ __launch_bounds__(256) void gemm_qkv(
    const u16* __restrict__ A, const u16* __restrict__ Bt,
    u16* __restrict__ Cv, const float* __restrict__ bias) {
    __shared__ u16 lA[128 * 64];
    __shared__ u16 lB[128 * 64];
    const int t = threadIdx.x;
    const int lane = t & 63;
    const int w = t >> 6;
    const int bm = blockIdx.x * 128, bn = blockIdx.y * 128;

    const int srow = t >> 3;
    const int csrc = ((t & 7) ^ (srow & 7)) * 8;
    const u16* gA0 = A + (long)(bm + srow) * 256 + csrc;
    const u16* gB0 = Bt + (long)(bn + srow) * 256 + csrc;

    const int wr = (w >> 1) * 64, wc = (w & 1) * 64;
    const int frow = lane & 15;
    const int kq = lane >> 4;

    f32x4 acc[4][4] = {};

    for (int k0 = 0; k0 < 256; k0 += 64) {
        __syncthreads();
#pragma unroll
        for (int p = 0; p < 4; ++p) {
            g2lds16(gA0 + (long)p * 32 * 256 + k0, &lA[p * 2048 + t * 8]);
            g2lds16(gB0 + (long)p * 32 * 256 + k0, &lB[p * 2048 + t * 8]);
        }
        __syncthreads();
#pragma unroll
        for (int kk = 0; kk < 2; ++kk) {
            const int sc = ((kk * 4 + kq) ^ (frow & 7)) * 8;
            bf16x8 af[4], bfr[4];
#pragma unroll
            for (int i = 0; i < 4; ++i)
                af[i] = *(const bf16x8*)&lA[(wr + i * 16 + frow) * 64 + sc];
#pragma unroll
            for (int j = 0; j < 4; ++j)
                bfr[j] = *(const bf16x8*)&lB[(wc + j * 16 + frow) * 64 + sc];
#pragma unroll
            for (int i = 0; i < 4; ++i)
#pragma unroll
                for (int j = 0; j < 4; ++j)
                    acc[i][j] = __builtin_amdgcn_mfma_f32_16x16x32_bf16(
                        af[i], bfr[j], acc[i][j], 0, 0, 0);
        }
    }

    const int crow0 = bm + wr + (lane >> 4) * 4;
    const int ccol0 = bn + wc + (lane & 15);
#pragma unroll
    for (int i = 0; i < 4; ++i)
#pragma unroll
        for (int j = 0; j < 4; ++j) {
            int col = ccol0 + j * 16;
#pragma unroll
            for (int r = 0; r < 4; ++r) {
                int row = crow0 + i * 16 + r;
                float v = acc[i][j][r] + bias[col];
                v = v > 0.0f ? v : 0.0f;
                if (col >= 1024) v *= SCALEF;
                Cv[(long)row * 1536 + col] = f2bf(v);
            }
        }
}

// ---------------------------------------------------------------------------
// v [b][n][h] (qkv cols 0..511) -> vt [b][h][n]
__global__ __launch_bounds__(256) void transpose_v(const u16* __restrict__ qkv,
                                                   u16* __restrict__ vt) {
    __shared__ u16 tile[64][72];
    const int t = threadIdx.x;
    const int b = blockIdx.z;
    const int n0 = blockIdx.x * 64, h0 = blockIdx.y * 64;
    const u16* src = qkv + (long)(b * NSEQ + n0) * 1536 + h0;
#pragma unroll
    for (int it = 0; it < 2; ++it) {
        int n = (t >> 3) + it * 32;
        int hc = (t & 7) * 8;
        *(bf16x8*)&tile[n][hc] = *(const bf16x8*)&src[(long)n * 1536 + hc];
    }
    __syncthreads();
    u16* dst = vt + ((long)b * HID + h0) * NSEQ + n0;
#pragma unroll
    for (int it = 0; it < 2; ++it) {
        int h = (t >> 3) + it * 32;
        int nc = (t & 7) * 8;
        bf16x8 v;
#pragma unroll
        for (int j = 0; j < 8; ++j) v[j] = (short)tile[nc + j][h];
        *(bf16x8*)&dst[(long)h * NSEQ + nc] = v;
    }
}

// ---------------------------------------------------------------------------
// Fused attention: per block = 64 q-rows of one batch, full HID output.
// No online softmax needed: post-relu q,k => s >= 0 and tiny (SCALE=1/2304);
// masked entries are exactly exp(-9e15)=0. So p = mask*exp(s) directly,
// row-sum l accumulated, O = sum p*v, normalized by 1/l at the end.
// 4 waves: wave w owns S cols [w*32,+32) in QK, O cols [w*128,+128) in PV.
__global__ __launch_bounds__(256, 2) void fused_attn(
    const u16* __restrict__ qkv, const u16* __restrict__ vt,
    const float* __restrict__ mask, float* __restrict__ out) {
    __shared__ u16 lQ[64 * 64];     //  8 KB
    __shared__ u16 lK[128 * 64];    // 16 KB
    __shared__ u16 lP[64 * 136];    // 17 KB (stride 136 u16 = 272B = 17*16B)
    __shared__ u16 lV[512 * 32];    // 32 KB
    __shared__ float lred[4][64];

    const int t = threadIdx.x;
    const int lane = t & 63;
    const int w = t >> 6;

    // XCD-bijective decode: 512 blocks, batch b -> XCD b&7
    const int f = (int)blockIdx.x;
    const int j = f >> 3;
    const int b = (f & 7) + 8 * (j >> 4);
    const int qt = j & 15;
    const int n0 = qt * 64;

    const u16* qb = qkv + (long)b * NSEQ * 1536 + 1024;  // q cols, SCALE folded
    const u16* kb = qkv + (long)b * NSEQ * 1536 + 512;
    const u16* vb = vt + (long)b * HID * NSEQ;
    const float* mb = mask + (long)b * NSEQ * NSEQ;

    const int frow = lane & 15;
    const int kq = lane >> 4;

    // staging coords
    const int srow = t >> 3;                       // 0..31
    const int csrc = ((t & 7) ^ (srow & 7)) * 8;   // Q/K 8-chunk XOR swizzle
    const int vrow = t >> 2;                       // 0..63 per pass
    const int vchunk = t & 3;

    f32x4 o_acc[4][8] = {};          // 128 f32: rows i*16, cols w*128+jo*16
    float lsum[16] = {};             // slot = i*4+r, row = i*16+(lane>>4)*4+r

    for (int kvt = 0; kvt < 8; ++kvt) {
        const int kv0 = kvt * 128;
        f32x4 s_acc[4][2] = {};

        // ---- QK^T over d (8 steps of 64) ----
        for (int d0 = 0; d0 < 512; d0 += 64) {
            __syncthreads();
#pragma unroll
            for (int p = 0; p < 2; ++p)
                g2lds16(qb + (long)(n0 + p * 32 + srow) * 1536 + d0 + csrc,
                        &lQ[p * 2048 + t * 8]);
#pragma unroll
            for (int p = 0; p < 4; ++p)
                g2lds16(kb + (long)(kv0 + p * 32 + srow) * 1536 + d0 + csrc,
                        &lK[p * 2048 + t * 8]);
            __syncthreads();
#pragma unroll
            for (int kk = 0; kk < 2; ++kk) {
                const int sc = ((kk * 4 + kq) ^ (frow & 7)) * 8;
                bf16x8 af[4], bf[2];
#pragma unroll
                for (int i = 0; i < 4; ++i)
                    af[i] = *(const bf16x8*)&lQ[(i * 16 + frow) * 64 + sc];
#pragma unroll
                for (int jq = 0; jq < 2; ++jq)
                    bf[jq] = *(const bf16x8*)&lK[(w * 32 + jq * 16 + frow) * 64 + sc];
#pragma unroll
                for (int i = 0; i < 4; ++i)
#pragma unroll
                    for (int jq = 0; jq < 2; ++jq)
                        s_acc[i][jq] = __builtin_amdgcn_mfma_f32_16x16x32_bf16(
                            af[i], bf[jq], s_acc[i][jq], 0, 0, 0);
            }
        }

        // ---- mask * exp -> P (bf16, LDS) + row-sum ----
        __syncthreads();   // prev PV readers done before overwriting lP
#pragma unroll
        for (int i = 0; i < 4; ++i)
#pragma unroll
            for (int jq = 0; jq < 2; ++jq) {
                const int col = w * 32 + jq * 16 + frow;
#pragma unroll
                for (int r = 0; r < 4; ++r) {
                    const int row = i * 16 + (lane >> 4) * 4 + r;
                    float mv = mb[(long)(n0 + row) * NSEQ + kv0 + col];
                    float p = mv * __expf(s_acc[i][jq][r]);
                    u16 pb = f2bf(p);
                    lP[row * 136 + col] = pb;
                    lsum[i * 4 + r] += bf2f(pb);
                }
            }

        // ---- PV: O += P * V over kv (4 steps of 32) ----
        for (int ks = 0; ks < 4; ++ks) {
            __syncthreads();
#pragma unroll
            for (int p = 0; p < 8; ++p) {
                const int vr = p * 64 + vrow;
                const int vc = (vchunk ^ (vr & 3)) * 8;
                g2lds16(vb + (long)vr * NSEQ + kv0 + ks * 32 + vc,
                        &lV[p * 2048 + t * 8]);
            }
            __syncthreads();
            bf16x8 ap[4];
#pragma unroll
            for (int i = 0; i < 4; ++i)
                ap[i] = *(const bf16x8*)&lP[(i * 16 + frow) * 136 + ks * 32 + kq * 8];
#pragma unroll
            for (int jo = 0; jo < 8; ++jo) {
                const int h = w * 128 + jo * 16 + frow;
                bf16x8 bv8 = *(const bf16x8*)&lV[h * 32 + ((kq ^ (h & 3)) * 8)];
#pragma unroll
                for (int i = 0; i < 4; ++i)
                    o_acc[i][jo] = __builtin_amdgcn_mfma_f32_16x16x32_bf16(
                        ap[i], bv8, o_acc[i][jo], 0, 0, 0);
            }
        }
    }

    // ---- row-sum reduce + normalize + relu + store ----
#pragma unroll
    for (int s = 0; s < 16; ++s) {
        lsum[s] += __shfl_xor(lsum[s], 1);
        lsum[s] += __shfl_xor(lsum[s], 2);
        lsum[s] += __shfl_xor(lsum[s], 4);
        lsum[s] += __shfl_xor(lsum[s], 8);
    }
    if ((lane & 15) == 0) {
#pragma unroll
        for (int i = 0; i < 4; ++i)
#pragma unroll
            for (int r = 0; r < 4; ++r)
                lred[w][i * 16 + (lane >> 4) * 4 + r] = lsum[i * 4 + r];
    }
    __syncthreads();
    float linv[16];
#pragma unroll
    for (int i = 0; i < 4; ++i)
#pragma unroll
        for (int r = 0; r < 4; ++r) {
            const int row = i * 16 + (lane >> 4) * 4 + r;
            linv[i * 4 + r] = 1.0f /
                (lred[0][row] + lred[1][row] + lred[2][row] + lred[3][row]);
        }
#pragma unroll
    for (int i = 0; i < 4; ++i)
#pragma unroll
        for (int jo = 0; jo < 8; ++jo) {
            const int col = w * 128 + jo * 16 + frow;
#pragma unroll
            for (int r = 0; r < 4; ++r) {
                const int row = n0 + i * 16 + (lane >> 4) * 4 + r;
                float v = o_acc[i][jo][r] * linv[i * 4 + r];
                out[((long)b * NSEQ + row) * HID + col] = v > 0.0f ? v : 0.0f;
            }
        }
}

// ---------------------------------------------------------------------------
extern "C" void kernel_launch(void* const* d_in, const int* in_sizes, int n_in,
                              void* d_out, int out_size, void* d_ws, size_t ws_size,
                              hipStream_t stream) {
    const float* x    = (const float*)d_in[0];
    const float* mask = (const float*)d_in[1];
    const float* Wv   = (const float*)d_in[2];
    const float* bv   = (const float*)d_in[3];
    const float* Wk   = (const float*)d_in[4];
    const float* bk   = (const float*)d_in[5];
    const float* Wq   = (const float*)d_in[6];
    const float* bq   = (const float*)d_in[7];
    float* out = (float*)d_out;

    char* ws = (char*)d_ws;
    u16*   xb      = (u16*)ws;   ws += (long)NBAT * NSEQ * DIN * 2;      // 16 MB
    u16*   Wtb     = (u16*)ws;   ws += (long)1536 * 256 * 2;             // 768 KB
    float* biascat = (float*)ws; ws += 1536 * 4;
    u16*   qkv     = (u16*)ws;   ws += (long)NBAT * NSEQ * 1536 * 2;     // 96 MB
    u16*   vt      = (u16*)ws;   ws += (long)NBAT * HID * NSEQ * 2;      // 32 MB

    prep_x<<<8192, 256, 0, stream>>>(x, xb);
    prep_w<<<1536, 256, 0, stream>>>(Wv, bv, Wk, bk, Wq, bq, Wtb, biascat);

    // qkv projections: [32768,256] x [1536,256]^T -> [32768,1536] bf16
    gemm_qkv<<<dim3(256, 12), 256, 0, stream>>>(xb, Wtb, qkv, biascat);

    transpose_v<<<dim3(16, 8, NBAT), 256, 0, stream>>>(qkv, vt);

    // fused scores+mask+softmax+PV: 32 batches x 16 q-tiles of 64 rows
    fused_attn<<<NBAT * 16, 256, 0, stream>>>(qkv, vt, mask, out);
}